// Round 3
// baseline (73.625 us; speedup 1.0000x reference)
//
#include <hip/hip_runtime.h>
#include <math.h>

// ElasticSparseAttention: B=1, H=16, KVH=4, S=2048, D=64, W=64, layer 12/24.
// One wave per (h,s). Lane (r,c), r=lane>>2, c=lane&3, owns window slot
// j = p*16+r across 4 phases. QK: quad-per-K-row fully-coalesced gather +
// quad shfl reduce. PV: same lane assignment -> e/idx are already lane-local;
// quad-coalesced V gather, accumulate per-dim-chunk, then shfl_xor reduce
// across the 16 r-lanes (offsets 4/8/16/32). Lanes 0-15 store the 256B row.

#define NH   16
#define SEQ  2048
#define HD   64
#define WIN  64

// Index-math constants folded in double exactly as Python does, then f32.
#define ALPHA_F ((float)(12.0 / 23.0))
#define PD0_F   ((float)(64.0 * (1.0 - 12.0 / 23.0)))
#define NEG_MIN (-3.4028234663852886e38f)

__global__ __launch_bounds__(256) void esa_kernel(
    const float* __restrict__ q,
    const float* __restrict__ k,
    const float* __restrict__ v,
    float* __restrict__ out)
{
    const int lane = threadIdx.x & 63;
    const int wid  = threadIdx.x >> 6;
    const int pair = blockIdx.x * 4 + wid;   // pair = h*SEQ + s
    const int h    = pair >> 11;
    const int s    = pair & (SEQ - 1);
    const int kvh  = h >> 2;

    __shared__ float qs[4][HD];
    qs[wid][lane] = q[(size_t)(h * SEQ + s) * HD + lane];
    __syncthreads();

    // ---- wave-uniform elastic params (bit-exact f32, no FMA contraction) ----
    const int   end     = (s > WIN - 1) ? s : (WIN - 1);
    const float ids_len = (float)(end + 1);
    const float pd      = __fadd_rn(PD0_F, __fmul_rn(ids_len, ALPHA_F));
    float start_f       = rintf(__fsub_rn(ids_len, pd));
    if (start_f < 0.0f) start_f = 0.0f;
    const int   start   = (int)start_f;
    const float window  = (float)(end + 1 - start);
    const float spacing = __fmul_rn(window, 0.015625f);   // /64 exact
    const float iw      = __fdiv_rn((float)h, 15.0f);
    const float omiw    = __fsub_rn(1.0f, iw);

    const int r = lane >> 2;   // window-slot-within-phase 0..15
    const int c = lane & 3;    // 16B chunk within 64B line, 0..3

    // hoisted q fragments: chunks c, c+4, c+8, c+12 (same for all phases)
    float4 qq[4];
    #pragma unroll
    for (int i = 0; i < 4; ++i)
        qq[i] = ((const float4*)qs[wid])[4 * i + c];

    const float* kbase = k + (size_t)kvh * SEQ * HD;
    const float* vbase = v + (size_t)kvh * SEQ * HD;

    // ---- QK: 4 phases x 16 rows; quad-per-row fully-coalesced gather ----
    float sc[4];
    int   idxar[4];
    #pragma unroll
    for (int p = 0; p < 4; ++p) {
        const int j    = p * 16 + r;
        const int rel0 = (int)rintf(__fmul_rn((float)j, spacing));
        const int rel1 = (int)rintf(__fmul_rn((float)(j + 1), spacing));
        const int basej    = start + rel0;      // over[:, :W]
        const int shiftedj = start + rel1 - 1;  // over[:, 1:] - 1
        const float idxf = __fadd_rn(__fmul_rn((float)basej, omiw),
                                     __fmul_rn((float)shiftedj, iw));
        int idx = (int)rintf(idxf);
        const bool valid = (idx <= s);
        if (!valid) idx = 0;
        idxar[p] = idx;

        const float4* krow = (const float4*)(kbase + (size_t)idx * HD);
        float dot = 0.0f;
        #pragma unroll
        for (int i = 0; i < 4; ++i) {
            float4 kk = krow[4 * i + c];
            dot += qq[i].x * kk.x + qq[i].y * kk.y
                 + qq[i].z * kk.z + qq[i].w * kk.w;
        }
        dot += __shfl_xor(dot, 1);              // reduce across the quad
        dot += __shfl_xor(dot, 2);
        sc[p] = valid ? dot * 0.125f : NEG_MIN;
    }

    // ---- softmax over 64 slots (values replicated x4 across c) ----
    float m = fmaxf(fmaxf(sc[0], sc[1]), fmaxf(sc[2], sc[3]));
    #pragma unroll
    for (int off = 4; off <= 32; off <<= 1) m = fmaxf(m, __shfl_xor(m, off));
    float e[4];
    float ssum = 0.0f;
    #pragma unroll
    for (int p = 0; p < 4; ++p) { e[p] = __expf(sc[p] - m); ssum += e[p]; }
    #pragma unroll
    for (int off = 4; off <= 32; off <<= 1) ssum += __shfl_xor(ssum, off);

    // ---- PV: e[p]/idxar[p] are already lane-local; same coalesced gather ----
    float4 acc[4];
    #pragma unroll
    for (int i = 0; i < 4; ++i) acc[i] = make_float4(0.f, 0.f, 0.f, 0.f);

    #pragma unroll
    for (int p = 0; p < 4; ++p) {
        const float4* vrow = (const float4*)(vbase + (size_t)idxar[p] * HD);
        const float ep = e[p];                  // 0 for masked slots
        #pragma unroll
        for (int i = 0; i < 4; ++i) {
            float4 vv = vrow[4 * i + c];
            acc[i].x += ep * vv.x; acc[i].y += ep * vv.y;
            acc[i].z += ep * vv.z; acc[i].w += ep * vv.w;
        }
    }

    // reduce across the 16 r-lanes (lane bits 2..5); c is preserved
    #pragma unroll
    for (int off = 4; off <= 32; off <<= 1) {
        #pragma unroll
        for (int i = 0; i < 4; ++i) {
            acc[i].x += __shfl_xor(acc[i].x, off);
            acc[i].y += __shfl_xor(acc[i].y, off);
            acc[i].z += __shfl_xor(acc[i].z, off);
            acc[i].w += __shfl_xor(acc[i].w, off);
        }
    }

    // lanes 0..15 store the full 256B row: lane writes chunk (i=lane>>2, c)
    if (lane < 16) {
        const int i = lane >> 2;                 // static-select, no scratch
        float4 o = (i == 0) ? acc[0] : (i == 1) ? acc[1]
                 : (i == 2) ? acc[2] : acc[3];
        const float inv = 1.0f / ssum;
        o.x *= inv; o.y *= inv; o.z *= inv; o.w *= inv;
        float4* dst = (float4*)(out + (size_t)(h * SEQ + s) * HD
                                + 16 * i + 4 * (lane & 3));
        *dst = o;
    }
}

extern "C" void kernel_launch(void* const* d_in, const int* in_sizes, int n_in,
                              void* d_out, int out_size, void* d_ws, size_t ws_size,
                              hipStream_t stream) {
    const float* q = (const float*)d_in[0];
    const float* k = (const float*)d_in[1];
    const float* v = (const float*)d_in[2];
    float* out = (float*)d_out;
    const int nblocks = NH * SEQ / 4;   // 4 waves/block, one (h,s) per wave
    esa_kernel<<<nblocks, 256, 0, stream>>>(q, k, v, out);
}

// Round 4
// 52.919 us; speedup vs baseline: 1.3913x; 1.3913x over previous
//
#include <hip/hip_runtime.h>
#include <math.h>

// ElasticSparseAttention: B=1, H=16, KVH=4, S=2048, D=64, W=64, layer 12/24.
// One wave per (h,s). Lane (r,c), r=lane>>2, c=lane&3, owns window slot
// j = p*16+r across 4 phases. QK: quad-per-K-row fully-coalesced gather +
// quad shfl reduce. PV: e/idx already lane-local; quad-coalesced V gather,
// accumulate per-chunk, full shfl_xor reduce across r-bits (STATIC acc
// indices only -- a runtime-indexed select here sends acc[] to scratch,
// which cost 131MB of HBM spill traffic in the previous round). Lanes 0..3
// store the 256B row as 4x64B fully-lined stores with static indices.

#define NH   16
#define SEQ  2048
#define HD   64
#define WIN  64

// Index-math constants folded in double exactly as Python does, then f32.
#define ALPHA_F ((float)(12.0 / 23.0))
#define PD0_F   ((float)(64.0 * (1.0 - 12.0 / 23.0)))
#define NEG_MIN (-3.4028234663852886e38f)

__global__ __launch_bounds__(256) void esa_kernel(
    const float* __restrict__ q,
    const float* __restrict__ k,
    const float* __restrict__ v,
    float* __restrict__ out)
{
    const int lane = threadIdx.x & 63;
    const int wid  = threadIdx.x >> 6;
    const int pair = blockIdx.x * 4 + wid;   // pair = h*SEQ + s
    const int h    = pair >> 11;
    const int s    = pair & (SEQ - 1);
    const int kvh  = h >> 2;

    __shared__ float qs[4][HD];
    qs[wid][lane] = q[(size_t)(h * SEQ + s) * HD + lane];
    __syncthreads();

    // ---- wave-uniform elastic params (bit-exact f32, no FMA contraction) ----
    const int   end     = (s > WIN - 1) ? s : (WIN - 1);
    const float ids_len = (float)(end + 1);
    const float pd      = __fadd_rn(PD0_F, __fmul_rn(ids_len, ALPHA_F));
    float start_f       = rintf(__fsub_rn(ids_len, pd));
    if (start_f < 0.0f) start_f = 0.0f;
    const int   start   = (int)start_f;
    const float window  = (float)(end + 1 - start);
    const float spacing = __fmul_rn(window, 0.015625f);   // /64 exact
    const float iw      = __fdiv_rn((float)h, 15.0f);
    const float omiw    = __fsub_rn(1.0f, iw);

    const int r = lane >> 2;   // window-slot-within-phase 0..15
    const int c = lane & 3;    // 16B chunk within 64B line, 0..3

    // hoisted q fragments: chunks c, c+4, c+8, c+12 (same for all phases)
    float4 qq[4];
    #pragma unroll
    for (int i = 0; i < 4; ++i)
        qq[i] = ((const float4*)qs[wid])[4 * i + c];

    const float* kbase = k + (size_t)kvh * SEQ * HD;
    const float* vbase = v + (size_t)kvh * SEQ * HD;

    // ---- QK: 4 phases x 16 rows; quad-per-row fully-coalesced gather ----
    float sc[4];
    int   idxar[4];
    #pragma unroll
    for (int p = 0; p < 4; ++p) {
        const int j    = p * 16 + r;
        const int rel0 = (int)rintf(__fmul_rn((float)j, spacing));
        const int rel1 = (int)rintf(__fmul_rn((float)(j + 1), spacing));
        const int basej    = start + rel0;      // over[:, :W]
        const int shiftedj = start + rel1 - 1;  // over[:, 1:] - 1
        const float idxf = __fadd_rn(__fmul_rn((float)basej, omiw),
                                     __fmul_rn((float)shiftedj, iw));
        int idx = (int)rintf(idxf);
        const bool valid = (idx <= s);
        if (!valid) idx = 0;
        idxar[p] = idx;

        const float4* krow = (const float4*)(kbase + (size_t)idx * HD);
        float dot = 0.0f;
        #pragma unroll
        for (int i = 0; i < 4; ++i) {
            float4 kk = krow[4 * i + c];
            dot += qq[i].x * kk.x + qq[i].y * kk.y
                 + qq[i].z * kk.z + qq[i].w * kk.w;
        }
        dot += __shfl_xor(dot, 1);              // reduce across the quad
        dot += __shfl_xor(dot, 2);
        sc[p] = valid ? dot * 0.125f : NEG_MIN;
    }

    // ---- softmax over 64 slots (values replicated x4 across c) ----
    float m = fmaxf(fmaxf(sc[0], sc[1]), fmaxf(sc[2], sc[3]));
    #pragma unroll
    for (int off = 4; off <= 32; off <<= 1) m = fmaxf(m, __shfl_xor(m, off));
    float e[4];
    float ssum = 0.0f;
    #pragma unroll
    for (int p = 0; p < 4; ++p) { e[p] = __expf(sc[p] - m); ssum += e[p]; }
    #pragma unroll
    for (int off = 4; off <= 32; off <<= 1) ssum += __shfl_xor(ssum, off);

    // ---- PV: e[p]/idxar[p] are already lane-local; same coalesced gather ----
    float4 acc[4];
    #pragma unroll
    for (int i = 0; i < 4; ++i) acc[i] = make_float4(0.f, 0.f, 0.f, 0.f);

    #pragma unroll
    for (int p = 0; p < 4; ++p) {
        const float4* vrow = (const float4*)(vbase + (size_t)idxar[p] * HD);
        const float ep = e[p];                  // 0 for masked slots
        #pragma unroll
        for (int i = 0; i < 4; ++i) {
            float4 vv = vrow[4 * i + c];
            acc[i].x += ep * vv.x; acc[i].y += ep * vv.y;
            acc[i].z += ep * vv.z; acc[i].w += ep * vv.w;
        }
    }

    // full reduce across the 16 r-lanes (lane bits 2..5); static indices only
    #pragma unroll
    for (int off = 4; off <= 32; off <<= 1) {
        #pragma unroll
        for (int i = 0; i < 4; ++i) {
            acc[i].x += __shfl_xor(acc[i].x, off);
            acc[i].y += __shfl_xor(acc[i].y, off);
            acc[i].z += __shfl_xor(acc[i].z, off);
            acc[i].w += __shfl_xor(acc[i].w, off);
        }
    }

    // lanes 0..3 (c = lane) each store all 4 chunks at orow[4*i + c]:
    // per i, the 4 lanes' float4s form one contiguous 64B line.
    if (lane < 4) {
        const float inv = 1.0f / ssum;
        float4* orow = (float4*)(out + (size_t)(h * SEQ + s) * HD);
        #pragma unroll
        for (int i = 0; i < 4; ++i) {
            float4 o = acc[i];
            o.x *= inv; o.y *= inv; o.z *= inv; o.w *= inv;
            orow[4 * i + lane] = o;
        }
    }
}

extern "C" void kernel_launch(void* const* d_in, const int* in_sizes, int n_in,
                              void* d_out, int out_size, void* d_ws, size_t ws_size,
                              hipStream_t stream) {
    const float* q = (const float*)d_in[0];
    const float* k = (const float*)d_in[1];
    const float* v = (const float*)d_in[2];
    float* out = (float*)d_out;
    const int nblocks = NH * SEQ / 4;   // 4 waves/block, one (h,s) per wave
    esa_kernel<<<nblocks, 256, 0, stream>>>(q, k, v, out);
}